// Round 12
// baseline (55.223 us; speedup 1.0000x reference)
//
#include <hip/hip_runtime.h>
#include <math.h>

#define DDIM 2048
#define KP 8
#define BLOCK 256

typedef float f4 __attribute__((ext_vector_type(4)));

#if __has_builtin(__builtin_amdgcn_fdot2_f32_bf16)
#define HAVE_DOT2 1
typedef __bf16 bf2 __attribute__((ext_vector_type(2)));
#else
#define HAVE_DOT2 0
#endif

#if __has_builtin(__builtin_amdgcn_update_dpp)
#define HAVE_DPP 1
#else
#define HAVE_DPP 0
#endif

__device__ __forceinline__ unsigned short f32_to_bf16_rne(float f) {
    unsigned u = __float_as_uint(f);
    unsigned r = u + 0x7FFFu + ((u >> 16) & 1u);
    return (unsigned short)(r >> 16);
}

__device__ __forceinline__ float gelu_f(float x) {
    // 0.5*x*(1+tanh(y)) == x * sigmoid(2y),  y = 0.79788456*(x+0.044715x^3)
    float x2 = x * x;
    float inner = x * fmaf(0.044715f, x2, 1.0f);
    float e = __expf(-1.5957691216057308f * inner);   // exp(-2y)
    return x * __builtin_amdgcn_rcpf(1.0f + e);
}

__device__ __forceinline__ float wave_reduce_add(float v) {
#pragma unroll
    for (int m = 32; m >= 1; m >>= 1) v += __shfl_xor(v, m, 64);
    return v;
}

#if HAVE_DPP
template <int CTRL>
__device__ __forceinline__ float dpp_add(float v) {
    int t = __builtin_amdgcn_update_dpp(0, __builtin_bit_cast(int, v),
                                        CTRL, 0xf, 0xf, true);
    return v + __builtin_bit_cast(float, t);
}
// Wave-64 sum entirely on the VALU pipe (no DS ops). Valid in LANE 63 ONLY.
__device__ __forceinline__ float wave_sum_dpp_lane63(float v) {
    v = dpp_add<0x111>(v);   // row_shr:1
    v = dpp_add<0x112>(v);   // row_shr:2
    v = dpp_add<0x114>(v);   // row_shr:4
    v = dpp_add<0x118>(v);   // row_shr:8  -> lane 15 of each row16 = row sum
    v = dpp_add<0x142>(v);   // row_bcast:15 -> lane63 = row3+row2
    v = dpp_add<0x143>(v);   // row_bcast:31 -> lane63 += (row0+row1)
    return v;
}
#endif

// Prologue: pb = bf16(protos) (32 KB, L1-resident for the main kernel);
// inv_pn[k] = 1/max(||bf16(proto_k)||, eps)  (norm of the ROUNDED values).
__global__ void proto_prep_kernel(const float* __restrict__ protos,
                                  unsigned short* __restrict__ pb,
                                  float* __restrict__ inv_pn) {
    const int k = blockIdx.x;
    const int tid = threadIdx.x;
    const float* p = protos + k * DDIM;
    float ss = 0.0f;
#pragma unroll
    for (int i = 0; i < 2; ++i) {
        int idx = tid + i * 256;                       // f4 index within row
        f4 a = reinterpret_cast<const f4*>(p)[idx];
        ushort4 u;
        u.x = f32_to_bf16_rne(a.x); u.y = f32_to_bf16_rne(a.y);
        u.z = f32_to_bf16_rne(a.z); u.w = f32_to_bf16_rne(a.w);
        float q;
        q = __uint_as_float((unsigned)u.x << 16); ss += q * q;
        q = __uint_as_float((unsigned)u.y << 16); ss += q * q;
        q = __uint_as_float((unsigned)u.z << 16); ss += q * q;
        q = __uint_as_float((unsigned)u.w << 16); ss += q * q;
        *reinterpret_cast<ushort4*>(&pb[(size_t)k * DDIM + idx * 4]) = u;
    }
    ss = wave_reduce_add(ss);
    __shared__ float red[4];
    const int wave = tid >> 6, lane = tid & 63;
    if (lane == 0) red[wave] = ss;
    __syncthreads();
    if (tid == 0)
        inv_pn[k] = 1.0f / fmaxf(sqrtf(red[0] + red[1] + red[2] + red[3]), 1e-12f);
}

// Block-per-row skeleton (R8) + DPP reduce (R10). R11: TWO rows per
// iteration -> two independent dependency chains interleaved in each wave,
// one barrier per pair, 18 reduction values per LDS round-trip. LSE max
// subtraction dropped (|z| <= tau, no overflow possible).
__global__ __launch_bounds__(BLOCK)
void fused_row_kernel(const float* __restrict__ x,
                      const unsigned short* __restrict__ pb,
                      const float* __restrict__ lt,
                      const float* __restrict__ lg,
                      const float* __restrict__ lb,
                      const float* __restrict__ inv_pn,
                      float* __restrict__ out, int nrows) {
    alignas(16) __shared__ float red[2][18][4];   // [buf][value][wave]

    const int tid = threadIdx.x;
    const int lane = tid & 63;
    const int wave = tid >> 6;

    const float tau = __expf(lt[0]);
    const float gamma = __expf(lg[0]);
    const float alpha = 1.0f / (1.0f + __expf(-lb[0]));
    const float inv_tau = 1.0f / tau;
    const float logK_div_tau = logf(8.0f) * inv_tau;

    float ipn[KP];
#pragma unroll
    for (int k = 0; k < KP; ++k) ipn[k] = inv_pn[k];

    const uint2* pb2 = reinterpret_cast<const uint2*>(pb);  // 4 bf16 per uint2
    const int G = gridDim.x;

    int buf = 0;
    for (int r0 = blockIdx.x; r0 < nrows; r0 += 2 * G) {
        const int r1 = r0 + G;
        const bool has1 = r1 < nrows;

        // issue all four loads up front: row1's loads fly under row0's gelu
        const f4* xr0 = reinterpret_cast<const f4*>(x + (size_t)r0 * DDIM);
        f4 a0 = xr0[tid];
        f4 b0 = xr0[tid + 256];
        f4 a1, b1;
        if (has1) {
            const f4* xr1 = reinterpret_cast<const f4*>(x + (size_t)r1 * DDIM);
            a1 = xr1[tid];
            b1 = xr1[tid + 256];
        } else {
            a1 = a0; b1 = b0;   // dummy, result unused
        }

        f4 g0a, g0b, g1a, g1b;
        g0a.x = gelu_f(a0.x); g0a.y = gelu_f(a0.y);
        g0a.z = gelu_f(a0.z); g0a.w = gelu_f(a0.w);
        g0b.x = gelu_f(b0.x); g0b.y = gelu_f(b0.y);
        g0b.z = gelu_f(b0.z); g0b.w = gelu_f(b0.w);
        g1a.x = gelu_f(a1.x); g1a.y = gelu_f(a1.y);
        g1a.z = gelu_f(a1.z); g1a.w = gelu_f(a1.w);
        g1b.x = gelu_f(b1.x); g1b.y = gelu_f(b1.y);
        g1b.z = gelu_f(b1.z); g1b.w = gelu_f(b1.w);

        float vals[18];
        vals[8] = g0a.x * g0a.x + g0a.y * g0a.y + g0a.z * g0a.z + g0a.w * g0a.w
                + g0b.x * g0b.x + g0b.y * g0b.y + g0b.z * g0b.z + g0b.w * g0b.w;
        vals[17] = g1a.x * g1a.x + g1a.y * g1a.y + g1a.z * g1a.z + g1a.w * g1a.w
                 + g1b.x * g1b.x + g1b.y * g1b.y + g1b.z * g1b.z + g1b.w * g1b.w;

#if HAVE_DOT2
        bf2 p0a, p0b, p0c, p0d, p1a, p1b, p1c, p1d;
        p0a.x = (__bf16)g0a.x; p0a.y = (__bf16)g0a.y;
        p0b.x = (__bf16)g0a.z; p0b.y = (__bf16)g0a.w;
        p0c.x = (__bf16)g0b.x; p0c.y = (__bf16)g0b.y;
        p0d.x = (__bf16)g0b.z; p0d.y = (__bf16)g0b.w;
        p1a.x = (__bf16)g1a.x; p1a.y = (__bf16)g1a.y;
        p1b.x = (__bf16)g1a.z; p1b.y = (__bf16)g1a.w;
        p1c.x = (__bf16)g1b.x; p1c.y = (__bf16)g1b.y;
        p1d.x = (__bf16)g1b.z; p1d.y = (__bf16)g1b.w;
#pragma unroll
        for (int k = 0; k < KP; ++k) {
            uint2 q0 = pb2[k * 512 + tid];
            uint2 q1 = pb2[k * 512 + 256 + tid];
            float t0, t1;
            t0 = __builtin_amdgcn_fdot2_f32_bf16(p0a, __builtin_bit_cast(bf2, q0.x), 0.0f, false);
            t1 = __builtin_amdgcn_fdot2_f32_bf16(p1a, __builtin_bit_cast(bf2, q0.x), 0.0f, false);
            t0 = __builtin_amdgcn_fdot2_f32_bf16(p0b, __builtin_bit_cast(bf2, q0.y), t0, false);
            t1 = __builtin_amdgcn_fdot2_f32_bf16(p1b, __builtin_bit_cast(bf2, q0.y), t1, false);
            t0 = __builtin_amdgcn_fdot2_f32_bf16(p0c, __builtin_bit_cast(bf2, q1.x), t0, false);
            t1 = __builtin_amdgcn_fdot2_f32_bf16(p1c, __builtin_bit_cast(bf2, q1.x), t1, false);
            t0 = __builtin_amdgcn_fdot2_f32_bf16(p0d, __builtin_bit_cast(bf2, q1.y), t0, false);
            t1 = __builtin_amdgcn_fdot2_f32_bf16(p1d, __builtin_bit_cast(bf2, q1.y), t1, false);
            vals[k] = t0;
            vals[9 + k] = t1;
        }
#else
#pragma unroll
        for (int k = 0; k < KP; ++k) {
            uint2 q0 = pb2[k * 512 + tid];
            uint2 q1 = pb2[k * 512 + 256 + tid];
            float c0 = __uint_as_float(q0.x << 16);
            float c1 = __uint_as_float(q0.x & 0xFFFF0000u);
            float c2 = __uint_as_float(q0.y << 16);
            float c3 = __uint_as_float(q0.y & 0xFFFF0000u);
            float c4 = __uint_as_float(q1.x << 16);
            float c5 = __uint_as_float(q1.x & 0xFFFF0000u);
            float c6 = __uint_as_float(q1.y << 16);
            float c7 = __uint_as_float(q1.y & 0xFFFF0000u);
            float t0, t1;
            t0 = fmaf(c0, g0a.x, c1 * g0a.y);
            t1 = fmaf(c0, g1a.x, c1 * g1a.y);
            t0 = fmaf(c2, g0a.z, t0); t0 = fmaf(c3, g0a.w, t0);
            t1 = fmaf(c2, g1a.z, t1); t1 = fmaf(c3, g1a.w, t1);
            t0 = fmaf(c4, g0b.x, t0); t0 = fmaf(c5, g0b.y, t0);
            t1 = fmaf(c4, g1b.x, t1); t1 = fmaf(c5, g1b.y, t1);
            t0 = fmaf(c6, g0b.z, t0); t0 = fmaf(c7, g0b.w, t0);
            t1 = fmaf(c6, g1b.z, t1); t1 = fmaf(c7, g1b.w, t1);
            vals[k] = t0;
            vals[9 + k] = t1;
        }
#endif

#if HAVE_DPP
#pragma unroll
        for (int v = 0; v < 18; ++v) vals[v] = wave_sum_dpp_lane63(vals[v]);
        if (lane == 63) {
#pragma unroll
            for (int v = 0; v < 18; ++v) red[buf][v][wave] = vals[v];
        }
#else
#pragma unroll
        for (int v = 0; v < 18; ++v) vals[v] = wave_reduce_add(vals[v]);
        if (lane == 0) {
#pragma unroll
            for (int v = 0; v < 18; ++v) red[buf][v][wave] = vals[v];
        }
#endif
        __syncthreads();   // ONE barrier per row pair (red double-buffered)

        float s[18];
#pragma unroll
        for (int v = 0; v < 18; ++v) {
            f4 r = *reinterpret_cast<const f4*>(red[buf][v]);  // broadcast b128
            s[v] = (r.x + r.y) + (r.z + r.w);
        }
        buf ^= 1;

        // gates, redundantly in every thread; no max-subtract (|z| <= tau)
        float gate0, gate1;
        {
            const float invn = 1.0f / fmaxf(sqrtf(s[8]), 1e-12f);
            float e = 0.0f;
#pragma unroll
            for (int k = 0; k < KP; ++k)
                e += __expf(s[k] * invn * ipn[k] * tau);
            float sms = __logf(e) * inv_tau - logK_div_tau;
            gate0 = 1.0f - alpha + alpha * __expf(-gamma * sms);
        }
        {
            const float invn = 1.0f / fmaxf(sqrtf(s[17]), 1e-12f);
            float e = 0.0f;
#pragma unroll
            for (int k = 0; k < KP; ++k)
                e += __expf(s[9 + k] * invn * ipn[k] * tau);
            float sms = __logf(e) * inv_tau - logK_div_tau;
            gate1 = 1.0f - alpha + alpha * __expf(-gamma * sms);
        }

        f4* o0 = reinterpret_cast<f4*>(out + (size_t)r0 * DDIM);
        f4 w0, w1;
        w0.x = g0a.x * gate0; w0.y = g0a.y * gate0;
        w0.z = g0a.z * gate0; w0.w = g0a.w * gate0;
        w1.x = g0b.x * gate0; w1.y = g0b.y * gate0;
        w1.z = g0b.z * gate0; w1.w = g0b.w * gate0;
        __builtin_nontemporal_store(w0, &o0[tid]);
        __builtin_nontemporal_store(w1, &o0[tid + 256]);
        if (has1) {
            f4* o1 = reinterpret_cast<f4*>(out + (size_t)r1 * DDIM);
            f4 w2, w3;
            w2.x = g1a.x * gate1; w2.y = g1a.y * gate1;
            w2.z = g1a.z * gate1; w2.w = g1a.w * gate1;
            w3.x = g1b.x * gate1; w3.y = g1b.y * gate1;
            w3.z = g1b.z * gate1; w3.w = g1b.w * gate1;
            __builtin_nontemporal_store(w2, &o1[tid]);
            __builtin_nontemporal_store(w3, &o1[tid + 256]);
        }
    }
}

extern "C" void kernel_launch(void* const* d_in, const int* in_sizes, int n_in,
                              void* d_out, int out_size, void* d_ws, size_t ws_size,
                              hipStream_t stream) {
    const float* x = (const float*)d_in[0];
    const float* protos = (const float*)d_in[1];
    const float* lt = (const float*)d_in[2];
    const float* lg = (const float*)d_in[3];
    const float* lb = (const float*)d_in[4];
    float* out = (float*)d_out;

    float* inv_pn = (float*)d_ws;                                // 8 floats
    unsigned short* pb = (unsigned short*)((char*)d_ws + 256);   // 32 KB bf16 protos

    const int nrows = in_sizes[0] / DDIM;

    proto_prep_kernel<<<KP, 256, 0, stream>>>(protos, pb, inv_pn);

    // 2048 blocks: 8 rows/block as 4 pair-iterations; ~all blocks co-resident
    int blocks = 2048;
    if (blocks > (nrows + 1) / 2) blocks = (nrows + 1) / 2;
    fused_row_kernel<<<blocks, BLOCK, 0, stream>>>(x, pb, lt, lg, lb, inv_pn,
                                                   out, nrows);
}

// Round 13
// 52.092 us; speedup vs baseline: 1.0601x; 1.0601x over previous
//
#include <hip/hip_runtime.h>
#include <math.h>

#define DDIM 2048
#define KP 8
#define BLOCK 256

typedef float f4 __attribute__((ext_vector_type(4)));

#if __has_builtin(__builtin_amdgcn_fdot2_f32_bf16)
#define HAVE_DOT2 1
typedef __bf16 bf2 __attribute__((ext_vector_type(2)));
#else
#define HAVE_DOT2 0
#endif

#if __has_builtin(__builtin_amdgcn_update_dpp)
#define HAVE_DPP 1
#else
#define HAVE_DPP 0
#endif

__device__ __forceinline__ unsigned short f32_to_bf16_rne(float f) {
    unsigned u = __float_as_uint(f);
    unsigned r = u + 0x7FFFu + ((u >> 16) & 1u);
    return (unsigned short)(r >> 16);
}

__device__ __forceinline__ float gelu_f(float x) {
    // 0.5*x*(1+tanh(y)) == x * sigmoid(2y),  y = 0.79788456*(x+0.044715x^3)
    float x2 = x * x;
    float inner = x * fmaf(0.044715f, x2, 1.0f);
    float e = __expf(-1.5957691216057308f * inner);   // exp(-2y)
    return x * __builtin_amdgcn_rcpf(1.0f + e);
}

__device__ __forceinline__ float wave_reduce_add(float v) {
#pragma unroll
    for (int m = 32; m >= 1; m >>= 1) v += __shfl_xor(v, m, 64);
    return v;
}

#if HAVE_DPP
template <int CTRL>
__device__ __forceinline__ float dpp_add(float v) {
    int t = __builtin_amdgcn_update_dpp(0, __builtin_bit_cast(int, v),
                                        CTRL, 0xf, 0xf, true);
    return v + __builtin_bit_cast(float, t);
}
// Wave-64 sum entirely on the VALU pipe (no DS ops). Valid in LANE 63 ONLY.
__device__ __forceinline__ float wave_sum_dpp_lane63(float v) {
    v = dpp_add<0x111>(v);   // row_shr:1
    v = dpp_add<0x112>(v);   // row_shr:2
    v = dpp_add<0x114>(v);   // row_shr:4
    v = dpp_add<0x118>(v);   // row_shr:8  -> lane 15 of each row16 = row sum
    v = dpp_add<0x142>(v);   // row_bcast:15 -> lane63 = row3+row2
    v = dpp_add<0x143>(v);   // row_bcast:31 -> lane63 += (row0+row1)
    return v;
}
#endif

// Prologue: pb = bf16(protos) (32 KB, L1-resident for the main kernel);
// inv_pn[k] = 1/max(||bf16(proto_k)||, eps)  (norm of the ROUNDED values).
__global__ void proto_prep_kernel(const float* __restrict__ protos,
                                  unsigned short* __restrict__ pb,
                                  float* __restrict__ inv_pn) {
    const int k = blockIdx.x;
    const int tid = threadIdx.x;
    const float* p = protos + k * DDIM;
    float ss = 0.0f;
#pragma unroll
    for (int i = 0; i < 2; ++i) {
        int idx = tid + i * 256;                       // f4 index within row
        f4 a = reinterpret_cast<const f4*>(p)[idx];
        ushort4 u;
        u.x = f32_to_bf16_rne(a.x); u.y = f32_to_bf16_rne(a.y);
        u.z = f32_to_bf16_rne(a.z); u.w = f32_to_bf16_rne(a.w);
        float q;
        q = __uint_as_float((unsigned)u.x << 16); ss += q * q;
        q = __uint_as_float((unsigned)u.y << 16); ss += q * q;
        q = __uint_as_float((unsigned)u.z << 16); ss += q * q;
        q = __uint_as_float((unsigned)u.w << 16); ss += q * q;
        *reinterpret_cast<ushort4*>(&pb[(size_t)k * DDIM + idx * 4]) = u;
    }
    ss = wave_reduce_add(ss);
    __shared__ float red[4];
    const int wave = tid >> 6, lane = tid & 63;
    if (lane == 0) red[wave] = ss;
    __syncthreads();
    if (tid == 0)
        inv_pn[k] = 1.0f / fmaxf(sqrtf(red[0] + red[1] + red[2] + red[3]), 1e-12f);
}

// R12: block-per-row skeleton (R8) + DPP reduce (R10) + 2-row pairing (R11)
// + cross-iteration prefetch (R9/R10 — dropping it was R11's regression).
// Next pair's loads are issued right after the current pair's x regs die,
// so dot+DPP+barrier+gate+store covers their HBM latency.
__global__ __launch_bounds__(BLOCK)
void fused_row_kernel(const float* __restrict__ x,
                      const unsigned short* __restrict__ pb,
                      const float* __restrict__ lt,
                      const float* __restrict__ lg,
                      const float* __restrict__ lb,
                      const float* __restrict__ inv_pn,
                      float* __restrict__ out, int nrows) {
    alignas(16) __shared__ float red[2][18][4];   // [buf][value][wave]

    const int tid = threadIdx.x;
    const int lane = tid & 63;
    const int wave = tid >> 6;

    const float tau = __expf(lt[0]);
    const float gamma = __expf(lg[0]);
    const float alpha = 1.0f / (1.0f + __expf(-lb[0]));
    const float inv_tau = 1.0f / tau;
    const float logK_div_tau = logf(8.0f) * inv_tau;

    float ipn[KP];
#pragma unroll
    for (int k = 0; k < KP; ++k) ipn[k] = inv_pn[k];

    const uint2* pb2 = reinterpret_cast<const uint2*>(pb);  // 4 bf16 per uint2
    const int G = gridDim.x;

    int buf = 0;
    int r0 = blockIdx.x;
    if (r0 >= nrows) return;

    // preload pair 0 (row r1 clamped branch-free if absent)
    f4 a0, b0, a1, b1;
    {
        const int r1c = (r0 + G < nrows) ? r0 + G : r0;
        const f4* x0 = reinterpret_cast<const f4*>(x + (size_t)r0 * DDIM);
        const f4* x1 = reinterpret_cast<const f4*>(x + (size_t)r1c * DDIM);
        a0 = x0[tid]; b0 = x0[tid + 256];
        a1 = x1[tid]; b1 = x1[tid + 256];
    }

    for (; r0 < nrows; r0 += 2 * G) {
        const int r1 = r0 + G;
        const bool has1 = r1 < nrows;

        f4 g0a, g0b, g1a, g1b;
        g0a.x = gelu_f(a0.x); g0a.y = gelu_f(a0.y);
        g0a.z = gelu_f(a0.z); g0a.w = gelu_f(a0.w);
        g0b.x = gelu_f(b0.x); g0b.y = gelu_f(b0.y);
        g0b.z = gelu_f(b0.z); g0b.w = gelu_f(b0.w);
        g1a.x = gelu_f(a1.x); g1a.y = gelu_f(a1.y);
        g1a.z = gelu_f(a1.z); g1a.w = gelu_f(a1.w);
        g1b.x = gelu_f(b1.x); g1b.y = gelu_f(b1.y);
        g1b.z = gelu_f(b1.z); g1b.w = gelu_f(b1.w);

        // prefetch next pair now that a*/b* are dead (clamped, branch-free)
        {
            const int n0 = r0 + 2 * G, n1 = r0 + 3 * G;
            const int n0c = (n0 < nrows) ? n0 : r0;
            const int n1c = (n1 < nrows) ? n1 : r0;
            const f4* xn0 = reinterpret_cast<const f4*>(x + (size_t)n0c * DDIM);
            const f4* xn1 = reinterpret_cast<const f4*>(x + (size_t)n1c * DDIM);
            a0 = xn0[tid]; b0 = xn0[tid + 256];
            a1 = xn1[tid]; b1 = xn1[tid + 256];
        }

        float vals[18];
        vals[8] = g0a.x * g0a.x + g0a.y * g0a.y + g0a.z * g0a.z + g0a.w * g0a.w
                + g0b.x * g0b.x + g0b.y * g0b.y + g0b.z * g0b.z + g0b.w * g0b.w;
        vals[17] = g1a.x * g1a.x + g1a.y * g1a.y + g1a.z * g1a.z + g1a.w * g1a.w
                 + g1b.x * g1b.x + g1b.y * g1b.y + g1b.z * g1b.z + g1b.w * g1b.w;

#if HAVE_DOT2
        bf2 p0a, p0b, p0c, p0d, p1a, p1b, p1c, p1d;
        p0a.x = (__bf16)g0a.x; p0a.y = (__bf16)g0a.y;
        p0b.x = (__bf16)g0a.z; p0b.y = (__bf16)g0a.w;
        p0c.x = (__bf16)g0b.x; p0c.y = (__bf16)g0b.y;
        p0d.x = (__bf16)g0b.z; p0d.y = (__bf16)g0b.w;
        p1a.x = (__bf16)g1a.x; p1a.y = (__bf16)g1a.y;
        p1b.x = (__bf16)g1a.z; p1b.y = (__bf16)g1a.w;
        p1c.x = (__bf16)g1b.x; p1c.y = (__bf16)g1b.y;
        p1d.x = (__bf16)g1b.z; p1d.y = (__bf16)g1b.w;
#pragma unroll
        for (int k = 0; k < KP; ++k) {
            uint2 q0 = pb2[k * 512 + tid];
            uint2 q1 = pb2[k * 512 + 256 + tid];
            float t0, t1;
            t0 = __builtin_amdgcn_fdot2_f32_bf16(p0a, __builtin_bit_cast(bf2, q0.x), 0.0f, false);
            t1 = __builtin_amdgcn_fdot2_f32_bf16(p1a, __builtin_bit_cast(bf2, q0.x), 0.0f, false);
            t0 = __builtin_amdgcn_fdot2_f32_bf16(p0b, __builtin_bit_cast(bf2, q0.y), t0, false);
            t1 = __builtin_amdgcn_fdot2_f32_bf16(p1b, __builtin_bit_cast(bf2, q0.y), t1, false);
            t0 = __builtin_amdgcn_fdot2_f32_bf16(p0c, __builtin_bit_cast(bf2, q1.x), t0, false);
            t1 = __builtin_amdgcn_fdot2_f32_bf16(p1c, __builtin_bit_cast(bf2, q1.x), t1, false);
            t0 = __builtin_amdgcn_fdot2_f32_bf16(p0d, __builtin_bit_cast(bf2, q1.y), t0, false);
            t1 = __builtin_amdgcn_fdot2_f32_bf16(p1d, __builtin_bit_cast(bf2, q1.y), t1, false);
            vals[k] = t0;
            vals[9 + k] = t1;
        }
#else
#pragma unroll
        for (int k = 0; k < KP; ++k) {
            uint2 q0 = pb2[k * 512 + tid];
            uint2 q1 = pb2[k * 512 + 256 + tid];
            float c0 = __uint_as_float(q0.x << 16);
            float c1 = __uint_as_float(q0.x & 0xFFFF0000u);
            float c2 = __uint_as_float(q0.y << 16);
            float c3 = __uint_as_float(q0.y & 0xFFFF0000u);
            float c4 = __uint_as_float(q1.x << 16);
            float c5 = __uint_as_float(q1.x & 0xFFFF0000u);
            float c6 = __uint_as_float(q1.y << 16);
            float c7 = __uint_as_float(q1.y & 0xFFFF0000u);
            float t0, t1;
            t0 = fmaf(c0, g0a.x, c1 * g0a.y);
            t1 = fmaf(c0, g1a.x, c1 * g1a.y);
            t0 = fmaf(c2, g0a.z, t0); t0 = fmaf(c3, g0a.w, t0);
            t1 = fmaf(c2, g1a.z, t1); t1 = fmaf(c3, g1a.w, t1);
            t0 = fmaf(c4, g0b.x, t0); t0 = fmaf(c5, g0b.y, t0);
            t1 = fmaf(c4, g1b.x, t1); t1 = fmaf(c5, g1b.y, t1);
            t0 = fmaf(c6, g0b.z, t0); t0 = fmaf(c7, g0b.w, t0);
            t1 = fmaf(c6, g1b.z, t1); t1 = fmaf(c7, g1b.w, t1);
            vals[k] = t0;
            vals[9 + k] = t1;
        }
#endif

#if HAVE_DPP
#pragma unroll
        for (int v = 0; v < 18; ++v) vals[v] = wave_sum_dpp_lane63(vals[v]);
        if (lane == 63) {
#pragma unroll
            for (int v = 0; v < 18; ++v) red[buf][v][wave] = vals[v];
        }
#else
#pragma unroll
        for (int v = 0; v < 18; ++v) vals[v] = wave_reduce_add(vals[v]);
        if (lane == 0) {
#pragma unroll
            for (int v = 0; v < 18; ++v) red[buf][v][wave] = vals[v];
        }
#endif
        __syncthreads();   // ONE barrier per row pair (red double-buffered)

        float s[18];
#pragma unroll
        for (int v = 0; v < 18; ++v) {
            f4 r = *reinterpret_cast<const f4*>(red[buf][v]);  // broadcast b128
            s[v] = (r.x + r.y) + (r.z + r.w);
        }
        buf ^= 1;

        // gates, redundantly in every thread; no max-subtract (|z| <= tau)
        float gate0, gate1;
        {
            const float invn = 1.0f / fmaxf(sqrtf(s[8]), 1e-12f);
            float e = 0.0f;
#pragma unroll
            for (int k = 0; k < KP; ++k)
                e += __expf(s[k] * invn * ipn[k] * tau);
            float sms = __logf(e) * inv_tau - logK_div_tau;
            gate0 = 1.0f - alpha + alpha * __expf(-gamma * sms);
        }
        {
            const float invn = 1.0f / fmaxf(sqrtf(s[17]), 1e-12f);
            float e = 0.0f;
#pragma unroll
            for (int k = 0; k < KP; ++k)
                e += __expf(s[9 + k] * invn * ipn[k] * tau);
            float sms = __logf(e) * inv_tau - logK_div_tau;
            gate1 = 1.0f - alpha + alpha * __expf(-gamma * sms);
        }

        f4* o0 = reinterpret_cast<f4*>(out + (size_t)r0 * DDIM);
        f4 w0, w1;
        w0.x = g0a.x * gate0; w0.y = g0a.y * gate0;
        w0.z = g0a.z * gate0; w0.w = g0a.w * gate0;
        w1.x = g0b.x * gate0; w1.y = g0b.y * gate0;
        w1.z = g0b.z * gate0; w1.w = g0b.w * gate0;
        __builtin_nontemporal_store(w0, &o0[tid]);
        __builtin_nontemporal_store(w1, &o0[tid + 256]);
        if (has1) {
            f4* o1 = reinterpret_cast<f4*>(out + (size_t)r1 * DDIM);
            f4 w2, w3;
            w2.x = g1a.x * gate1; w2.y = g1a.y * gate1;
            w2.z = g1a.z * gate1; w2.w = g1a.w * gate1;
            w3.x = g1b.x * gate1; w3.y = g1b.y * gate1;
            w3.z = g1b.z * gate1; w3.w = g1b.w * gate1;
            __builtin_nontemporal_store(w2, &o1[tid]);
            __builtin_nontemporal_store(w3, &o1[tid + 256]);
        }
    }
}

extern "C" void kernel_launch(void* const* d_in, const int* in_sizes, int n_in,
                              void* d_out, int out_size, void* d_ws, size_t ws_size,
                              hipStream_t stream) {
    const float* x = (const float*)d_in[0];
    const float* protos = (const float*)d_in[1];
    const float* lt = (const float*)d_in[2];
    const float* lg = (const float*)d_in[3];
    const float* lb = (const float*)d_in[4];
    float* out = (float*)d_out;

    float* inv_pn = (float*)d_ws;                                // 8 floats
    unsigned short* pb = (unsigned short*)((char*)d_ws + 256);   // 32 KB bf16 protos

    const int nrows = in_sizes[0] / DDIM;

    proto_prep_kernel<<<KP, 256, 0, stream>>>(protos, pb, inv_pn);

    // 2048 blocks: 4 pair-iterations each (16384 rows); prefetch covers HBM lat
    int blocks = 2048;
    if (blocks > (nrows + 1) / 2) blocks = (nrows + 1) / 2;
    fused_row_kernel<<<blocks, BLOCK, 0, stream>>>(x, pb, lt, lg, lb, inv_pn,
                                                   out, nrows);
}